// Round 11
// baseline (842.907 us; speedup 1.0000x reference)
//
#include <hip/hip_runtime.h>
#include <math.h>

// VQ via split-fp16 MFMA emulation of fp32 GEMM.
// Round 11: occupancy 2x. 32-point blocks, 8 waves x (32x64) tile:
// acc 32 AGPR + ~90 arch VGPR -> 4 waves/SIMD, 2 blocks/CU (LDS ~37 KB).
// B frags direct global->VGPR depth-2 (per-wave-private, L2-served); A from
// LDS single-buffered; fn read from LDS at tile epilogue. No barriers, no
// manual waitcnt (compiler inserts counted waits; TLP covers latency).
// MFMA per-chain order (hh,hm,mh; ks ascending) identical -> decisions exact.
// x [32,256,32,32] f32, codebook [8192,256] f32.
// d2 = (||f||^2 - 2 f.c) + ||c||^2, argmin over 8192 codes, np association.
// f.c = 2^-26 * MFMA(h/m split of 8192*f, 8192*c): products hh+hm+mh.
// Outputs: codes [32,256,32,32] f32 then indices [32,32,32] (as float).

typedef _Float16 v8h __attribute__((ext_vector_type(8)));
typedef float f32x16 __attribute__((ext_vector_type(16)));
typedef unsigned int u32;

#define MFMA16 __builtin_amdgcn_mfma_f32_32x32x16_f16

__global__ __launch_bounds__(256) void cnorm_k(const float4* __restrict__ cb4,
                                               float* __restrict__ cn) {
  int lane = threadIdx.x & 63;
  int row = (blockIdx.x << 2) + (threadIdx.x >> 6);
  float4 v = cb4[(size_t)row * 64 + lane];
  float s = v.x * v.x + v.y * v.y + v.z * v.z + v.w * v.w;
#pragma unroll
  for (int off = 32; off > 0; off >>= 1) s += __shfl_xor(s, off, 64);
  if (lane == 0) cn[row] = s;
}

// Pre-split codebook into h/m fp16 planes. Granule g = ct*16+ks = 32 KB laid out
// [w(8)][pl(2)][hi(2)][c64(64)][8]; per-wave chunk = 2048 halves (4 KB).
// value = plane of 8192*cb[ct*512 + w*64 + c64][ks*16 + hi*8 + i].
__global__ __launch_bounds__(256) void split_cb(const float4* __restrict__ cb4,
                                                _Float16* __restrict__ W) {
  const int j = threadIdx.x & 31;
  const int ks = j >> 1, hi = j & 1;
  const int r = (blockIdx.x << 3) + (threadIdx.x >> 5);  // code row 0..8191
  const float4* src = cb4 + (size_t)r * 64 + (ks << 2) + (hi << 1);
  float4 v0 = src[0], v1 = src[1];
  float t[8] = {v0.x, v0.y, v0.z, v0.w, v1.x, v1.y, v1.z, v1.w};
  v8h hv, mv;
#pragma unroll
  for (int i = 0; i < 8; ++i) {
    float vs = t[i] * 8192.f;
    _Float16 h = (_Float16)vs;
    _Float16 m = (_Float16)(vs - (float)h);
    hv[i] = h; mv[i] = m;
  }
  const int wv = (r >> 6) & 7, c64 = r & 63;
  _Float16* base = W + ((size_t)((r >> 9) << 4) + ks) * 16384 + (wv << 11);
  *(v8h*)(base + (hi << 9) + (c64 << 3)) = hv;           // pl=0
  *(v8h*)(base + 1024 + (hi << 9) + (c64 << 3)) = mv;    // pl=1
}

__global__ void __launch_bounds__(512, 4) vq_fast(const float* __restrict__ x,
                                                  const float4* __restrict__ cb4,
                                                  const float* __restrict__ cn,
                                                  const _Float16* __restrict__ W,
                                                  float* __restrict__ out) {
  // A fragment-linear: [ks][pl][hi][col][8] -> contiguous conflict-free b128.
  __shared__ __align__(16) _Float16 F2L[16][2][2][32][8];  // 32 KB
  __shared__ float fnP[32][16];
  __shared__ float fnS[32];
  __shared__ float wredS[8][32];
  __shared__ u32  wredC[8][32];
  __shared__ u32  finS[32];

  const int tid = threadIdx.x;
  const int lane = tid & 63;
  const int w = tid >> 6;
  const int col = lane & 31;
  const int hi = lane >> 5;
  const int b = blockIdx.x >> 5;   // 0..31
  const int h = blockIdx.x & 31;   // 0..31 ; points: w-coord 0..31

  const char* Wb = (const char*)W;
  // byte offset of this lane's bh0 fragment within a 32 KB granule:
  // bh1 = +512 B (codes +32), bm0 = +2048 B (plane 1), bm1 = +2560 B.
  const size_t boff = (size_t)((w << 12) + (hi << 10) + (col << 4));

  // ---- prologue: issue B loads for granules 0,1 (latency hides under F stage)
  v8h Bf[2][4];
  {
    const v8h* b0 = (const v8h*)(Wb + boff);
    Bf[0][0] = b0[0];  Bf[0][1] = b0[32];  Bf[0][2] = b0[128];  Bf[0][3] = b0[160];
    const v8h* b1 = (const v8h*)(Wb + 32768 + boff);
    Bf[1][0] = b1[0];  Bf[1][1] = b1[32];  Bf[1][2] = b1[128];  Bf[1][3] = b1[160];
  }

  // ---- stage F splits (scaled by 2^13) + fn partials. thread = (grp, w32):
  // grp = k-slice ks (16 channels), w32 = point.
  {
    const float* xb = x + ((size_t)b << 18) + (h << 5);
    const int w32 = tid & 31, grp = tid >> 5;
    float s = 0.f;
#pragma unroll
    for (int h2 = 0; h2 < 2; ++h2) {
      v8h hv, mv;
#pragma unroll
      for (int i = 0; i < 8; ++i) {
        const int c = (grp << 4) + (h2 << 3) + i;
        float v = xb[(size_t)c * 1024 + w32];   // coalesced: w32 = point
        s += v * v;
        float vs = v * 8192.f;
        _Float16 hh = (_Float16)vs;
        _Float16 mm = (_Float16)(vs - (float)hh);
        hv[i] = hh; mv[i] = mm;
      }
      *(v8h*)&F2L[grp][0][h2][w32][0] = hv;
      *(v8h*)&F2L[grp][1][h2][w32][0] = mv;
    }
    fnP[w32][grp] = s;
  }
  __syncthreads();   // F2L + fnP visible
  if (tid < 32) {
    float t = 0.f;
#pragma unroll
    for (int j = 0; j < 16; ++j) t += fnP[tid][j];
    fnS[tid] = t;
  }
  __syncthreads();   // fnS visible — last barrier before the final reductions

  f32x16 a0, a1;
#pragma unroll
  for (int r = 0; r < 16; ++r) { a0[r] = 0.f; a1[r] = 0.f; }
  float mn[16];
#pragma unroll
  for (int sl = 0; sl < 16; ++sl) mn[sl] = INFINITY;
  u32 idp[4] = {0, 0, 0, 0};

  // ---- main loop: 16 code tiles (512 codes) x 16 k-steps; no barriers
#pragma unroll 1
  for (int ct = 0; ct < 16; ++ct) {
    const float cnv0 = cn[(ct << 9) + (w << 6) + col];
    const float cnv1 = cn[(ct << 9) + (w << 6) + 32 + col];
#pragma unroll
    for (int ks = 0; ks < 16; ++ks) {
      const int st = (ct << 4) + ks;
      const int P = ks & 1;
      // A frags from LDS (single-buffered; TLP covers the lgkm latency)
      const v8h ah = *(const v8h*)&F2L[ks][0][hi][col][0];
      const v8h am = *(const v8h*)&F2L[ks][1][hi][col][0];
      // 6 MFMAs; per-chain order hh, hm, mh (ks ascending) — bit-exact
      a0 = MFMA16(ah, Bf[P][0], a0, 0, 0, 0);
      a1 = MFMA16(ah, Bf[P][1], a1, 0, 0, 0);
      a0 = MFMA16(ah, Bf[P][2], a0, 0, 0, 0);
      a1 = MFMA16(ah, Bf[P][3], a1, 0, 0, 0);
      a0 = MFMA16(am, Bf[P][0], a0, 0, 0, 0);
      a1 = MFMA16(am, Bf[P][1], a1, 0, 0, 0);
      // depth-2 refill: granule st+2 into the just-consumed parity
      if (st < 254) {
        const v8h* bsrc = (const v8h*)(Wb + (((size_t)(st + 2)) << 15) + boff);
        Bf[P][0] = bsrc[0];
        Bf[P][1] = bsrc[32];   // +512 B
        Bf[P][2] = bsrc[128];  // +2048 B
        Bf[P][3] = bsrc[160];  // +2560 B
      }
    }
    // ---- tile epilogue: s = (fn - 2*dot) + cn, running argmin (fn from LDS)
#pragma unroll
    for (int sl = 0; sl < 16; ++sl) {
      const int row = (sl & 3) + ((sl >> 2) << 3) + (hi << 2);
      const float base = fnS[row];
      const u32 sh = (u32)((sl & 3) << 3);
      {
        float s = (base + (-0x1p-25f) * a0[sl]) + cnv0;
        const bool better = s < mn[sl];
        const u32 curv = idp[sl >> 2];
        const u32 upd = (curv & ~(255u << sh)) | (((u32)(ct << 1)) << sh);
        idp[sl >> 2] = better ? upd : curv;
        mn[sl] = better ? s : mn[sl];
      }
      {
        float s = (base + (-0x1p-25f) * a1[sl]) + cnv1;
        const bool better = s < mn[sl];
        const u32 curv = idp[sl >> 2];
        const u32 upd = (curv & ~(255u << sh)) | (((u32)((ct << 1) | 1)) << sh);
        idp[sl >> 2] = better ? upd : curv;
        mn[sl] = better ? s : mn[sl];
      }
    }
#pragma unroll
    for (int r = 0; r < 16; ++r) { a0[r] = 0.f; a1[r] = 0.f; }
  }

  // ---- final reduction: per-slot butterfly over 32 col-lanes, then cross-wave
#pragma unroll
  for (int sl = 0; sl < 16; ++sl) {
    float v = mn[sl];
    const u32 byte = (idp[sl >> 2] >> ((sl & 3) << 3)) & 255u;
    u32 code = ((byte >> 1) << 9) + ((u32)w << 6) + ((byte & 1) << 5) + (u32)col;
#pragma unroll
    for (int off = 1; off < 32; off <<= 1) {
      float v2 = __shfl_xor(v, off, 64);
      u32 c2 = (u32)__shfl_xor((int)code, off, 64);
      if (v2 < v || (v2 == v && c2 < code)) { v = v2; code = c2; }
    }
    if (col == 0) {
      const int row = (sl & 3) + ((sl >> 2) << 3) + (hi << 2);
      wredS[w][row] = v; wredC[w][row] = code;
    }
  }
  __syncthreads();
  if (tid < 32) {
    float bv = wredS[0][tid]; u32 bc = wredC[0][tid];
#pragma unroll
    for (int j = 1; j < 8; ++j) {
      float vv = wredS[j][tid]; u32 cc = wredC[j][tid];
      if (vv < bv || (vv == bv && cc < bc)) { bv = vv; bc = cc; }
    }
    finS[tid] = bc;
    // indices output [b,h,w] as float, offset = 32*256*32*32
    out[(size_t)8388608 + ((size_t)b << 10) + (h << 5) + tid] = (float)bc;
  }
  __syncthreads();

  // ---- codes gather: out[b,c,h,w] = codebook[idx][c]
  {
    const int pt = tid & 31, cg = tid >> 5;  // 16 channel groups
    const u32 code = finS[pt];
    const float4* cbr = cb4 + ((size_t)code << 6);
    const size_t obase = ((size_t)b << 18) + (h << 5) + pt;
#pragma unroll
    for (int cc = 0; cc < 4; ++cc) {
      const int c4 = (cc << 4) + cg;
      float4 vv = cbr[c4];
      out[obase + (size_t)((c4 << 2) + 0) * 1024] = vv.x;
      out[obase + (size_t)((c4 << 2) + 1) * 1024] = vv.y;
      out[obase + (size_t)((c4 << 2) + 2) * 1024] = vv.z;
      out[obase + (size_t)((c4 << 2) + 3) * 1024] = vv.w;
    }
  }
}

// ---------------- fallback (round-3 kernel, used only if ws too small) -------
__global__ void __launch_bounds__(512, 2) vq_fb(const float* __restrict__ x,
                                                const float4* __restrict__ cb4,
                                                const float* __restrict__ cn,
                                                float* __restrict__ out) {
  __shared__ __align__(16) _Float16 F2[2][64][264];
  __shared__ __align__(16) _Float16 Bsh[512][72];
  __shared__ float fnP[64][8];
  __shared__ float fnS[64];
  __shared__ float wredS[8][64];
  __shared__ u32  wredC[8][64];
  __shared__ u32  finS[64];

  const int tid = threadIdx.x;
  const int lane = tid & 63;
  const int w = tid >> 6;
  const int col = lane & 31;
  const int hi = lane >> 5;
  const int b = blockIdx.x >> 4;
  const int h0 = (blockIdx.x & 15) << 1;

  float4 rg[8];
  {
    const float4* src = cb4 + ((size_t)tid << 6);
#pragma unroll
    for (int j = 0; j < 8; ++j) rg[j] = src[j];
  }
  {
    const float* xb = x + ((size_t)b << 18) + (h0 << 5);
    float s = 0.f;
#pragma unroll
    for (int j = 0; j < 4; ++j) {
      v8h hv, mv;
#pragma unroll
      for (int i = 0; i < 8; ++i) {
        const int c = (w << 5) + (j << 3) + i;
        float v = xb[(size_t)c * 1024 + lane];
        s += v * v;
        float vs = v * 8192.f;
        _Float16 h = (_Float16)vs;
        _Float16 m = (_Float16)(vs - (float)h);
        hv[i] = h; mv[i] = m;
      }
      *(v8h*)&F2[0][lane][(w << 5) + (j << 3)] = hv;
      *(v8h*)&F2[1][lane][(w << 5) + (j << 3)] = mv;
    }
    fnP[lane][w] = s;
  }
  __syncthreads();
  if (tid < 64) {
    float t = 0.f;
#pragma unroll
    for (int j = 0; j < 8; ++j) t += fnP[tid][j];
    fnS[tid] = t;
  }
  {
#pragma unroll
    for (int j = 0; j < 4; ++j) {
      float t0[8] = {rg[2*j].x, rg[2*j].y, rg[2*j].z, rg[2*j].w,
                     rg[2*j+1].x, rg[2*j+1].y, rg[2*j+1].z, rg[2*j+1].w};
      v8h hv, mv;
#pragma unroll
      for (int i = 0; i < 8; ++i) {
        float vs = t0[i] * 8192.f;
        _Float16 h = (_Float16)vs;
        _Float16 m = (_Float16)(vs - (float)h);
        hv[i] = h; mv[i] = m;
      }
      *(v8h*)&Bsh[tid][(j << 3)] = hv;
      *(v8h*)&Bsh[tid][32 + (j << 3)] = mv;
    }
  }
  __syncthreads();

  float fnr[32];
#pragma unroll
  for (int sl = 0; sl < 32; ++sl) {
    const int row = ((sl >> 4) << 5) + (sl & 3) + (((sl >> 2) & 3) << 3) + (hi << 2);
    fnr[sl] = fnS[row];
  }

  f32x16 acc[2][2];
#pragma unroll
  for (int r = 0; r < 16; ++r) {
    acc[0][0][r] = 0.f; acc[0][1][r] = 0.f; acc[1][0][r] = 0.f; acc[1][1][r] = 0.f;
  }
  float mn[32];
#pragma unroll
  for (int sl = 0; sl < 32; ++sl) mn[sl] = INFINITY;
  u32 idp[8] = {0, 0, 0, 0, 0, 0, 0, 0};
  float cnv0 = 0.f, cnv1 = 0.f;

  for (int st = 0; st < 128; ++st) {
    const int ks = st & 7, ct = st >> 3;
    if (st < 127) {
      const int tn = st + 1;
      const float4* src = cb4 + ((size_t)((((tn >> 3) << 9) + tid)) << 6) + ((tn & 7) << 3);
#pragma unroll
      for (int j = 0; j < 8; ++j) rg[j] = src[j];
    }
    if (ks == 0) {
      cnv0 = cn[(ct << 9) + (w << 6) + col];
      cnv1 = cn[(ct << 9) + (w << 6) + 32 + col];
    }
    const int kb = ks << 5;
#pragma unroll
    for (int kh = 0; kh < 2; ++kh) {
      const int ko = kb + (kh << 4) + (hi << 3);
      const v8h ah0 = *(const v8h*)&F2[0][col][ko];
      const v8h ah1 = *(const v8h*)&F2[0][32 + col][ko];
      const v8h am0 = *(const v8h*)&F2[1][col][ko];
      const v8h am1 = *(const v8h*)&F2[1][32 + col][ko];
      const int bo = (kh << 4) + (hi << 3);
      const v8h bh0 = *(const v8h*)&Bsh[(w << 6) + col][bo];
      const v8h bh1 = *(const v8h*)&Bsh[(w << 6) + 32 + col][bo];
      const v8h bm0 = *(const v8h*)&Bsh[(w << 6) + col][32 + bo];
      const v8h bm1 = *(const v8h*)&Bsh[(w << 6) + 32 + col][32 + bo];
      acc[0][0] = MFMA16(ah0, bh0, acc[0][0], 0, 0, 0);
      acc[0][0] = MFMA16(ah0, bm0, acc[0][0], 0, 0, 0);
      acc[0][0] = MFMA16(am0, bh0, acc[0][0], 0, 0, 0);
      acc[0][1] = MFMA16(ah0, bh1, acc[0][1], 0, 0, 0);
      acc[0][1] = MFMA16(ah0, bm1, acc[0][1], 0, 0, 0);
      acc[0][1] = MFMA16(am0, bh1, acc[0][1], 0, 0, 0);
      acc[1][0] = MFMA16(ah1, bh0, acc[1][0], 0, 0, 0);
      acc[1][0] = MFMA16(ah1, bm0, acc[1][0], 0, 0, 0);
      acc[1][0] = MFMA16(am1, bh0, acc[1][0], 0, 0, 0);
      acc[1][1] = MFMA16(ah1, bh1, acc[1][1], 0, 0, 0);
      acc[1][1] = MFMA16(ah1, bm1, acc[1][1], 0, 0, 0);
      acc[1][1] = MFMA16(am1, bh1, acc[1][1], 0, 0, 0);
    }
    if (ks == 7) {
#pragma unroll
      for (int sl = 0; sl < 32; ++sl) {
        const int Mb = sl >> 4, reg = sl & 15;
        const float base = fnr[sl];
        const u32 sh = (u32)((sl & 3) << 3);
        {
          float s = (base + (-0x1p-25f) * acc[Mb][0][reg]) + cnv0;
          const bool better = s < mn[sl];
          const u32 curv = idp[sl >> 2];
          const u32 upd = (curv & ~(255u << sh)) | (((u32)(ct << 1)) << sh);
          idp[sl >> 2] = better ? upd : curv;
          mn[sl] = better ? s : mn[sl];
        }
        {
          float s = (base + (-0x1p-25f) * acc[Mb][1][reg]) + cnv1;
          const bool better = s < mn[sl];
          const u32 curv = idp[sl >> 2];
          const u32 upd = (curv & ~(255u << sh)) | (((u32)((ct << 1) | 1)) << sh);
          idp[sl >> 2] = better ? upd : curv;
          mn[sl] = better ? s : mn[sl];
        }
      }
#pragma unroll
      for (int r = 0; r < 16; ++r) {
        acc[0][0][r] = 0.f; acc[0][1][r] = 0.f; acc[1][0][r] = 0.f; acc[1][1][r] = 0.f;
      }
    }
    v8h cr[8];
    if (st < 127) {
#pragma unroll
      for (int j = 0; j < 4; ++j) {
        float t0[8] = {rg[2*j].x, rg[2*j].y, rg[2*j].z, rg[2*j].w,
                       rg[2*j+1].x, rg[2*j+1].y, rg[2*j+1].z, rg[2*j+1].w};
#pragma unroll
        for (int i = 0; i < 8; ++i) {
          float vs = t0[i] * 8192.f;
          _Float16 h = (_Float16)vs;
          _Float16 m = (_Float16)(vs - (float)h);
          cr[j][i] = h; cr[4 + j][i] = m;
        }
      }
    }
    __syncthreads();
    if (st < 127) {
#pragma unroll
      for (int j = 0; j < 4; ++j) {
        *(v8h*)&Bsh[tid][(j << 3)] = cr[j];
        *(v8h*)&Bsh[tid][32 + (j << 3)] = cr[4 + j];
      }
    }
    __syncthreads();
  }

#pragma unroll
  for (int sl = 0; sl < 32; ++sl) {
    float v = mn[sl];
    const u32 byte = (idp[sl >> 2] >> ((sl & 3) << 3)) & 255u;
    u32 code = ((byte >> 1) << 9) + ((u32)w << 6) + ((byte & 1) << 5) + (u32)col;
#pragma unroll
    for (int off = 1; off < 32; off <<= 1) {
      float v2 = __shfl_xor(v, off, 64);
      u32 c2 = (u32)__shfl_xor((int)code, off, 64);
      if (v2 < v || (v2 == v && c2 < code)) { v = v2; code = c2; }
    }
    if (col == 0) {
      const int row = ((sl >> 4) << 5) + (sl & 3) + (((sl >> 2) & 3) << 3) + (hi << 2);
      wredS[w][row] = v; wredC[w][row] = code;
    }
  }
  __syncthreads();
  if (tid < 64) {
    float bv = wredS[0][tid]; u32 bc = wredC[0][tid];
#pragma unroll
    for (int j = 1; j < 8; ++j) {
      float vv = wredS[j][tid]; u32 cc = wredC[j][tid];
      if (vv < bv || (vv == bv && cc < bc)) { bv = vv; bc = cc; }
    }
    finS[tid] = bc;
    out[(size_t)8388608 + ((size_t)b << 10) + (h0 << 5) + tid] = (float)bc;
  }
  __syncthreads();
  {
    const int pt = tid & 63, cg = tid >> 6;
    const u32 code = finS[pt];
    const float4* cbr = cb4 + ((size_t)code << 6);
    const size_t obase = ((size_t)b << 18) + (h0 << 5) + pt;
#pragma unroll
    for (int cc = 0; cc < 8; ++cc) {
      const int c4 = (cc << 3) + cg;
      float4 vv = cbr[c4];
      out[obase + (size_t)((c4 << 2) + 0) * 1024] = vv.x;
      out[obase + (size_t)((c4 << 2) + 1) * 1024] = vv.y;
      out[obase + (size_t)((c4 << 2) + 2) * 1024] = vv.z;
      out[obase + (size_t)((c4 << 2) + 3) * 1024] = vv.w;
    }
  }
}

extern "C" void kernel_launch(void* const* d_in, const int* in_sizes, int n_in,
                              void* d_out, int out_size, void* d_ws, size_t ws_size,
                              hipStream_t stream) {
  const float* x = (const float*)d_in[0];
  const float* cb = (const float*)d_in[1];
  float* out = (float*)d_out;
  float* cnorm = (float*)d_ws;  // 8192 floats at ws[0:32KB)

  cnorm_k<<<2048, 256, 0, stream>>>((const float4*)cb, cnorm);
  if (ws_size >= (size_t)32768 + (size_t)8388608) {
    _Float16* W = (_Float16*)((char*)d_ws + 32768);  // 8 MB split-permuted planes
    split_cb<<<1024, 256, 0, stream>>>((const float4*)cb, W);
    vq_fast<<<1024, 512, 0, stream>>>(x, (const float4*)cb, cnorm, W, out);
  } else {
    vq_fb<<<512, 512, 0, stream>>>(x, (const float4*)cb, cnorm, out);
  }
}

// Round 12
// 517.803 us; speedup vs baseline: 1.6279x; 1.6279x over previous
//
#include <hip/hip_runtime.h>
#include <math.h>

// VQ via split-fp16 MFMA emulation of fp32 GEMM.
// Round 12: 4 waves/SIMD (2 blocks/CU) with the PROVEN gll-staged structure.
// 32-pt blocks, 8 waves x (32x64) tile, acc=32 AGPR; B per-wave-private
// SINGLE-buffered Bsh via global_load_lds (R7 hazard order: ds_read -> lgkm0
// -> gll overwrite -> MFMA -> vmcnt0). A in 32KB fragment-linear LDS.
// Per-(pt,code) MFMA chain hh,hm,mh; ks ascending == R6 bit-exact.
// x [32,256,32,32] f32, codebook [8192,256] f32.
// d2 = (||f||^2 - 2 f.c) + ||c||^2, argmin over 8192 codes, np association.
// f.c = 2^-26 * MFMA(h/m split of 8192*f, 8192*c): products hh+hm+mh.
// Outputs: codes [32,256,32,32] f32 then indices [32,32,32] (as float).

typedef _Float16 v8h __attribute__((ext_vector_type(8)));
typedef float f32x16 __attribute__((ext_vector_type(16)));
typedef unsigned int u32;

#define MFMA16 __builtin_amdgcn_mfma_f32_32x32x16_f16

__device__ __forceinline__ void gll16(const _Float16* g, _Float16* l) {
  __builtin_amdgcn_global_load_lds(
      (const __attribute__((address_space(1))) void*)(const void*)g,
      (__attribute__((address_space(3))) void*)(void*)l, 16, 0, 0);
}

__global__ __launch_bounds__(256) void cnorm_k(const float4* __restrict__ cb4,
                                               float* __restrict__ cn) {
  int lane = threadIdx.x & 63;
  int row = (blockIdx.x << 2) + (threadIdx.x >> 6);
  float4 v = cb4[(size_t)row * 64 + lane];
  float s = v.x * v.x + v.y * v.y + v.z * v.z + v.w * v.w;
#pragma unroll
  for (int off = 32; off > 0; off >>= 1) s += __shfl_xor(s, off, 64);
  if (lane == 0) cn[row] = s;
}

// Pre-split codebook into h/m fp16 planes. Granule g = ct*16+ks = 32 KB laid out
// [w(8)][pl(2)][hi(2)][c64(64)][8]; per-wave chunk = 2048 halves (4 KB).
// value = plane of 8192*cb[ct*512 + w*64 + c64][ks*16 + hi*8 + i].
__global__ __launch_bounds__(256) void split_cb(const float4* __restrict__ cb4,
                                                _Float16* __restrict__ W) {
  const int j = threadIdx.x & 31;
  const int ks = j >> 1, hi = j & 1;
  const int r = (blockIdx.x << 3) + (threadIdx.x >> 5);  // code row 0..8191
  const float4* src = cb4 + (size_t)r * 64 + (ks << 2) + (hi << 1);
  float4 v0 = src[0], v1 = src[1];
  float t[8] = {v0.x, v0.y, v0.z, v0.w, v1.x, v1.y, v1.z, v1.w};
  v8h hv, mv;
#pragma unroll
  for (int i = 0; i < 8; ++i) {
    float vs = t[i] * 8192.f;
    _Float16 h = (_Float16)vs;
    _Float16 m = (_Float16)(vs - (float)h);
    hv[i] = h; mv[i] = m;
  }
  const int wv = (r >> 6) & 7, c64 = r & 63;
  _Float16* base = W + ((size_t)((r >> 9) << 4) + ks) * 16384 + (wv << 11);
  *(v8h*)(base + (hi << 9) + (c64 << 3)) = hv;           // pl=0
  *(v8h*)(base + 1024 + (hi << 9) + (c64 << 3)) = mv;    // pl=1
}

__global__ void __launch_bounds__(512, 4) vq_fast(const float* __restrict__ x,
                                                  const float4* __restrict__ cb4,
                                                  const float* __restrict__ cn,
                                                  const _Float16* __restrict__ W,
                                                  float* __restrict__ out) {
  // A fragment-linear: [ks][pl][hi][col][8] -> contiguous conflict-free b128.
  __shared__ __align__(16) _Float16 F2L[16][2][2][32][8];  // 32 KB
  __shared__ __align__(16) _Float16 Bsh[8][2048];          // 32 KB, single-buf
  __shared__ float fnP[32][16];
  __shared__ float fnS[32];
  __shared__ float wredS[8][32];
  __shared__ u32  wredC[8][32];
  __shared__ u32  finS[32];

  const int tid = threadIdx.x;
  const int lane = tid & 63;
  const int w = tid >> 6;
  const int col = lane & 31;
  const int hi = lane >> 5;
  const int b = blockIdx.x >> 5;   // 0..31
  const int h = blockIdx.x & 31;   // 0..31

  const int rb0 = (hi << 9) + (col << 3);  // bh0 in wave chunk; +256=bh1, +1024=bm0, +1280=bm1

  // ---- prologue: stage granule 0 into this wave's Bsh chunk
  {
    const _Float16* s0 = W + (w << 11) + (lane << 3);
#pragma unroll
    for (int k = 0; k < 4; ++k) gll16(s0 + (k << 9), &Bsh[w][k << 9]);
  }

  // ---- stage F splits (scaled by 2^13) + fn partials. thread = (grp, w32)
  {
    const float* xb = x + ((size_t)b << 18) + (h << 5);
    const int w32 = tid & 31, grp = tid >> 5;   // grp = k-slice 0..15
    float s = 0.f;
#pragma unroll
    for (int h2 = 0; h2 < 2; ++h2) {
      v8h hv, mv;
#pragma unroll
      for (int i = 0; i < 8; ++i) {
        const int c = (grp << 4) + (h2 << 3) + i;
        float v = xb[(size_t)c * 1024 + w32];   // coalesced: w32 = point
        s += v * v;
        float vs = v * 8192.f;
        _Float16 hh = (_Float16)vs;
        _Float16 mm = (_Float16)(vs - (float)hh);
        hv[i] = hh; mv[i] = mm;
      }
      *(v8h*)&F2L[grp][0][h2][w32][0] = hv;
      *(v8h*)&F2L[grp][1][h2][w32][0] = mv;
    }
    fnP[w32][grp] = s;
  }
  __syncthreads();   // F2L + fnP visible; prologue glls drained
  if (tid < 32) {
    float t = 0.f;
#pragma unroll
    for (int j = 0; j < 16; ++j) t += fnP[tid][j];
    fnS[tid] = t;
  }
  __syncthreads();   // fnS visible — last barrier before the final reductions

  f32x16 a0, a1;
#pragma unroll
  for (int r = 0; r < 16; ++r) { a0[r] = 0.f; a1[r] = 0.f; }
  float mn[16];
#pragma unroll
  for (int sl = 0; sl < 16; ++sl) mn[sl] = INFINITY;
  u32 idp[4] = {0, 0, 0, 0};

  // ---- main loop: 16 code tiles (512 codes) x 16 k-steps; no barriers
#pragma unroll 1
  for (int ct = 0; ct < 16; ++ct) {
    const float cnv0 = cn[(ct << 9) + (w << 6) + col];
    const float cnv1 = cn[(ct << 9) + (w << 6) + 32 + col];
#pragma unroll
    for (int ks = 0; ks < 16; ++ks) {
      const int st = (ct << 4) + ks;
      // frags for step st (Bsh[w] holds granule st)
      const v8h ah  = *(const v8h*)&F2L[ks][0][hi][col][0];
      const v8h am  = *(const v8h*)&F2L[ks][1][hi][col][0];
      const v8h bh0 = *(const v8h*)&Bsh[w][rb0];
      const v8h bh1 = *(const v8h*)&Bsh[w][rb0 + 256];
      const v8h bm0 = *(const v8h*)&Bsh[w][rb0 + 1024];
      const v8h bm1 = *(const v8h*)&Bsh[w][rb0 + 1280];
      asm volatile("s_waitcnt lgkmcnt(0)" ::: "memory");  // frags in regs
      __builtin_amdgcn_sched_barrier(0);
      // stage granule st+1 into the just-read chunk (per-wave private)
      if (st < 255) {
        const _Float16* gsrc = W + ((size_t)(st + 1) << 14) + (w << 11) + (lane << 3);
        gll16(gsrc,        &Bsh[w][0]);
        gll16(gsrc + 512,  &Bsh[w][512]);
        gll16(gsrc + 1024, &Bsh[w][1024]);
        gll16(gsrc + 1536, &Bsh[w][1536]);
      }
      // 6 MFMAs; per-(pt,code) chain order hh, hm, mh (bit-identical to R6)
      a0 = MFMA16(ah, bh0, a0, 0, 0, 0);
      a1 = MFMA16(ah, bh1, a1, 0, 0, 0);
      a0 = MFMA16(ah, bm0, a0, 0, 0, 0);
      a1 = MFMA16(ah, bm1, a1, 0, 0, 0);
      a0 = MFMA16(am, bh0, a0, 0, 0, 0);
      a1 = MFMA16(am, bh1, a1, 0, 0, 0);
      asm volatile("s_waitcnt vmcnt(0)" ::: "memory");    // granule st+1 landed
      __builtin_amdgcn_sched_barrier(0);
    }
    // ---- tile epilogue: s = (fn - 2*dot) + cn, running argmin (fn from LDS)
#pragma unroll
    for (int sl = 0; sl < 16; ++sl) {
      const int row = (sl & 3) + ((sl >> 2) << 3) + (hi << 2);
      const float base = fnS[row];
      const u32 sh = (u32)((sl & 3) << 3);
      {
        float s = (base + (-0x1p-25f) * a0[sl]) + cnv0;
        const bool better = s < mn[sl];
        const u32 curv = idp[sl >> 2];
        const u32 upd = (curv & ~(255u << sh)) | (((u32)(ct << 1)) << sh);
        idp[sl >> 2] = better ? upd : curv;
        mn[sl] = better ? s : mn[sl];
      }
      {
        float s = (base + (-0x1p-25f) * a1[sl]) + cnv1;
        const bool better = s < mn[sl];
        const u32 curv = idp[sl >> 2];
        const u32 upd = (curv & ~(255u << sh)) | (((u32)((ct << 1) | 1)) << sh);
        idp[sl >> 2] = better ? upd : curv;
        mn[sl] = better ? s : mn[sl];
      }
    }
#pragma unroll
    for (int r = 0; r < 16; ++r) { a0[r] = 0.f; a1[r] = 0.f; }
  }

  // ---- final reduction: per-slot butterfly over 32 col-lanes, then cross-wave
#pragma unroll
  for (int sl = 0; sl < 16; ++sl) {
    float v = mn[sl];
    const u32 byte = (idp[sl >> 2] >> ((sl & 3) << 3)) & 255u;
    u32 code = ((byte >> 1) << 9) + ((u32)w << 6) + ((byte & 1) << 5) + (u32)col;
#pragma unroll
    for (int off = 1; off < 32; off <<= 1) {
      float v2 = __shfl_xor(v, off, 64);
      u32 c2 = (u32)__shfl_xor((int)code, off, 64);
      if (v2 < v || (v2 == v && c2 < code)) { v = v2; code = c2; }
    }
    if (col == 0) {
      const int row = (sl & 3) + ((sl >> 2) << 3) + (hi << 2);
      wredS[w][row] = v; wredC[w][row] = code;
    }
  }
  __syncthreads();
  if (tid < 32) {
    float bv = wredS[0][tid]; u32 bc = wredC[0][tid];
#pragma unroll
    for (int j = 1; j < 8; ++j) {
      float vv = wredS[j][tid]; u32 cc = wredC[j][tid];
      if (vv < bv || (vv == bv && cc < bc)) { bv = vv; bc = cc; }
    }
    finS[tid] = bc;
    // indices output [b,h,w] as float, offset = 32*256*32*32
    out[(size_t)8388608 + ((size_t)b << 10) + (h << 5) + tid] = (float)bc;
  }
  __syncthreads();

  // ---- codes gather: out[b,c,h,w] = codebook[idx][c]
  {
    const int pt = tid & 31, cg = tid >> 5;  // 16 channel groups
    const u32 code = finS[pt];
    const float4* cbr = cb4 + ((size_t)code << 6);
    const size_t obase = ((size_t)b << 18) + (h << 5) + pt;
#pragma unroll
    for (int cc = 0; cc < 4; ++cc) {
      const int c4 = (cc << 4) + cg;
      float4 vv = cbr[c4];
      out[obase + (size_t)((c4 << 2) + 0) * 1024] = vv.x;
      out[obase + (size_t)((c4 << 2) + 1) * 1024] = vv.y;
      out[obase + (size_t)((c4 << 2) + 2) * 1024] = vv.z;
      out[obase + (size_t)((c4 << 2) + 3) * 1024] = vv.w;
    }
  }
}

// ---------------- fallback (round-3 kernel, used only if ws too small) -------
__global__ void __launch_bounds__(512, 2) vq_fb(const float* __restrict__ x,
                                                const float4* __restrict__ cb4,
                                                const float* __restrict__ cn,
                                                float* __restrict__ out) {
  __shared__ __align__(16) _Float16 F2[2][64][264];
  __shared__ __align__(16) _Float16 Bsh[512][72];
  __shared__ float fnP[64][8];
  __shared__ float fnS[64];
  __shared__ float wredS[8][64];
  __shared__ u32  wredC[8][64];
  __shared__ u32  finS[64];

  const int tid = threadIdx.x;
  const int lane = tid & 63;
  const int w = tid >> 6;
  const int col = lane & 31;
  const int hi = lane >> 5;
  const int b = blockIdx.x >> 4;
  const int h0 = (blockIdx.x & 15) << 1;

  float4 rg[8];
  {
    const float4* src = cb4 + ((size_t)tid << 6);
#pragma unroll
    for (int j = 0; j < 8; ++j) rg[j] = src[j];
  }
  {
    const float* xb = x + ((size_t)b << 18) + (h0 << 5);
    float s = 0.f;
#pragma unroll
    for (int j = 0; j < 4; ++j) {
      v8h hv, mv;
#pragma unroll
      for (int i = 0; i < 8; ++i) {
        const int c = (w << 5) + (j << 3) + i;
        float v = xb[(size_t)c * 1024 + lane];
        s += v * v;
        float vs = v * 8192.f;
        _Float16 h = (_Float16)vs;
        _Float16 m = (_Float16)(vs - (float)h);
        hv[i] = h; mv[i] = m;
      }
      *(v8h*)&F2[0][lane][(w << 5) + (j << 3)] = hv;
      *(v8h*)&F2[1][lane][(w << 5) + (j << 3)] = mv;
    }
    fnP[lane][w] = s;
  }
  __syncthreads();
  if (tid < 64) {
    float t = 0.f;
#pragma unroll
    for (int j = 0; j < 8; ++j) t += fnP[tid][j];
    fnS[tid] = t;
  }
  {
#pragma unroll
    for (int j = 0; j < 4; ++j) {
      float t0[8] = {rg[2*j].x, rg[2*j].y, rg[2*j].z, rg[2*j].w,
                     rg[2*j+1].x, rg[2*j+1].y, rg[2*j+1].z, rg[2*j+1].w};
      v8h hv, mv;
#pragma unroll
      for (int i = 0; i < 8; ++i) {
        float vs = t0[i] * 8192.f;
        _Float16 h = (_Float16)vs;
        _Float16 m = (_Float16)(vs - (float)h);
        hv[i] = h; mv[i] = m;
      }
      *(v8h*)&Bsh[tid][(j << 3)] = hv;
      *(v8h*)&Bsh[tid][32 + (j << 3)] = mv;
    }
  }
  __syncthreads();

  float fnr[32];
#pragma unroll
  for (int sl = 0; sl < 32; ++sl) {
    const int row = ((sl >> 4) << 5) + (sl & 3) + (((sl >> 2) & 3) << 3) + (hi << 2);
    fnr[sl] = fnS[row];
  }

  f32x16 acc[2][2];
#pragma unroll
  for (int r = 0; r < 16; ++r) {
    acc[0][0][r] = 0.f; acc[0][1][r] = 0.f; acc[1][0][r] = 0.f; acc[1][1][r] = 0.f;
  }
  float mn[32];
#pragma unroll
  for (int sl = 0; sl < 32; ++sl) mn[sl] = INFINITY;
  u32 idp[8] = {0, 0, 0, 0, 0, 0, 0, 0};
  float cnv0 = 0.f, cnv1 = 0.f;

  for (int st = 0; st < 128; ++st) {
    const int ks = st & 7, ct = st >> 3;
    if (st < 127) {
      const int tn = st + 1;
      const float4* src = cb4 + ((size_t)((((tn >> 3) << 9) + tid)) << 6) + ((tn & 7) << 3);
#pragma unroll
      for (int j = 0; j < 8; ++j) rg[j] = src[j];
    }
    if (ks == 0) {
      cnv0 = cn[(ct << 9) + (w << 6) + col];
      cnv1 = cn[(ct << 9) + (w << 6) + 32 + col];
    }
    const int kb = ks << 5;
#pragma unroll
    for (int kh = 0; kh < 2; ++kh) {
      const int ko = kb + (kh << 4) + (hi << 3);
      const v8h ah0 = *(const v8h*)&F2[0][col][ko];
      const v8h ah1 = *(const v8h*)&F2[0][32 + col][ko];
      const v8h am0 = *(const v8h*)&F2[1][col][ko];
      const v8h am1 = *(const v8h*)&F2[1][32 + col][ko];
      const int bo = (kh << 4) + (hi << 3);
      const v8h bh0 = *(const v8h*)&Bsh[(w << 6) + col][bo];
      const v8h bh1 = *(const v8h*)&Bsh[(w << 6) + 32 + col][bo];
      const v8h bm0 = *(const v8h*)&Bsh[(w << 6) + col][32 + bo];
      const v8h bm1 = *(const v8h*)&Bsh[(w << 6) + 32 + col][32 + bo];
      acc[0][0] = MFMA16(ah0, bh0, acc[0][0], 0, 0, 0);
      acc[0][0] = MFMA16(ah0, bm0, acc[0][0], 0, 0, 0);
      acc[0][0] = MFMA16(am0, bh0, acc[0][0], 0, 0, 0);
      acc[0][1] = MFMA16(ah0, bh1, acc[0][1], 0, 0, 0);
      acc[0][1] = MFMA16(ah0, bm1, acc[0][1], 0, 0, 0);
      acc[0][1] = MFMA16(am0, bh1, acc[0][1], 0, 0, 0);
      acc[1][0] = MFMA16(ah1, bh0, acc[1][0], 0, 0, 0);
      acc[1][0] = MFMA16(ah1, bm0, acc[1][0], 0, 0, 0);
      acc[1][0] = MFMA16(am1, bh0, acc[1][0], 0, 0, 0);
      acc[1][1] = MFMA16(ah1, bh1, acc[1][1], 0, 0, 0);
      acc[1][1] = MFMA16(ah1, bm1, acc[1][1], 0, 0, 0);
      acc[1][1] = MFMA16(am1, bh1, acc[1][1], 0, 0, 0);
    }
    if (ks == 7) {
#pragma unroll
      for (int sl = 0; sl < 32; ++sl) {
        const int Mb = sl >> 4, reg = sl & 15;
        const float base = fnr[sl];
        const u32 sh = (u32)((sl & 3) << 3);
        {
          float s = (base + (-0x1p-25f) * acc[Mb][0][reg]) + cnv0;
          const bool better = s < mn[sl];
          const u32 curv = idp[sl >> 2];
          const u32 upd = (curv & ~(255u << sh)) | (((u32)(ct << 1)) << sh);
          idp[sl >> 2] = better ? upd : curv;
          mn[sl] = better ? s : mn[sl];
        }
        {
          float s = (base + (-0x1p-25f) * acc[Mb][1][reg]) + cnv1;
          const bool better = s < mn[sl];
          const u32 curv = idp[sl >> 2];
          const u32 upd = (curv & ~(255u << sh)) | (((u32)((ct << 1) | 1)) << sh);
          idp[sl >> 2] = better ? upd : curv;
          mn[sl] = better ? s : mn[sl];
        }
      }
#pragma unroll
      for (int r = 0; r < 16; ++r) {
        acc[0][0][r] = 0.f; acc[0][1][r] = 0.f; acc[1][0][r] = 0.f; acc[1][1][r] = 0.f;
      }
    }
    v8h cr[8];
    if (st < 127) {
#pragma unroll
      for (int j = 0; j < 4; ++j) {
        float t0[8] = {rg[2*j].x, rg[2*j].y, rg[2*j].z, rg[2*j].w,
                       rg[2*j+1].x, rg[2*j+1].y, rg[2*j+1].z, rg[2*j+1].w};
#pragma unroll
        for (int i = 0; i < 8; ++i) {
          float vs = t0[i] * 8192.f;
          _Float16 h = (_Float16)vs;
          _Float16 m = (_Float16)(vs - (float)h);
          cr[j][i] = h; cr[4 + j][i] = m;
        }
      }
    }
    __syncthreads();
    if (st < 127) {
#pragma unroll
      for (int j = 0; j < 4; ++j) {
        *(v8h*)&Bsh[tid][(j << 3)] = cr[j];
        *(v8h*)&Bsh[tid][32 + (j << 3)] = cr[4 + j];
      }
    }
    __syncthreads();
  }

#pragma unroll
  for (int sl = 0; sl < 32; ++sl) {
    float v = mn[sl];
    const u32 byte = (idp[sl >> 2] >> ((sl & 3) << 3)) & 255u;
    u32 code = ((byte >> 1) << 9) + ((u32)w << 6) + ((byte & 1) << 5) + (u32)col;
#pragma unroll
    for (int off = 1; off < 32; off <<= 1) {
      float v2 = __shfl_xor(v, off, 64);
      u32 c2 = (u32)__shfl_xor((int)code, off, 64);
      if (v2 < v || (v2 == v && c2 < code)) { v = v2; code = c2; }
    }
    if (col == 0) {
      const int row = ((sl >> 4) << 5) + (sl & 3) + (((sl >> 2) & 3) << 3) + (hi << 2);
      wredS[w][row] = v; wredC[w][row] = code;
    }
  }
  __syncthreads();
  if (tid < 64) {
    float bv = wredS[0][tid]; u32 bc = wredC[0][tid];
#pragma unroll
    for (int j = 1; j < 8; ++j) {
      float vv = wredS[j][tid]; u32 cc = wredC[j][tid];
      if (vv < bv || (vv == bv && cc < bc)) { bv = vv; bc = cc; }
    }
    finS[tid] = bc;
    out[(size_t)8388608 + ((size_t)b << 10) + (h0 << 5) + tid] = (float)bc;
  }
  __syncthreads();
  {
    const int pt = tid & 63, cg = tid >> 6;
    const u32 code = finS[pt];
    const float4* cbr = cb4 + ((size_t)code << 6);
    const size_t obase = ((size_t)b << 18) + (h0 << 5) + pt;
#pragma unroll
    for (int cc = 0; cc < 8; ++cc) {
      const int c4 = (cc << 3) + cg;
      float4 vv = cbr[c4];
      out[obase + (size_t)((c4 << 2) + 0) * 1024] = vv.x;
      out[obase + (size_t)((c4 << 2) + 1) * 1024] = vv.y;
      out[obase + (size_t)((c4 << 2) + 2) * 1024] = vv.z;
      out[obase + (size_t)((c4 << 2) + 3) * 1024] = vv.w;
    }
  }
}

extern "C" void kernel_launch(void* const* d_in, const int* in_sizes, int n_in,
                              void* d_out, int out_size, void* d_ws, size_t ws_size,
                              hipStream_t stream) {
  const float* x = (const float*)d_in[0];
  const float* cb = (const float*)d_in[1];
  float* out = (float*)d_out;
  float* cnorm = (float*)d_ws;  // 8192 floats at ws[0:32KB)

  cnorm_k<<<2048, 256, 0, stream>>>((const float4*)cb, cnorm);
  if (ws_size >= (size_t)32768 + (size_t)8388608) {
    _Float16* W = (_Float16*)((char*)d_ws + 32768);  // 8 MB split-permuted planes
    split_cb<<<1024, 256, 0, stream>>>((const float4*)cb, W);
    vq_fast<<<1024, 512, 0, stream>>>(x, (const float4*)cb, cnorm, W, out);
  } else {
    vq_fb<<<512, 512, 0, stream>>>(x, (const float4*)cb, cnorm, out);
  }
}

// Round 13
// 441.729 us; speedup vs baseline: 1.9082x; 1.1722x over previous
//
#include <hip/hip_runtime.h>
#include <math.h>

// VQ via split-fp16 MFMA emulation of fp32 GEMM.
// Round 13: R6-EXACT kernel (441 us, absmax 0) + wave phase-stagger.
// Theory: per-step accounting shows LDS(36%)+MFMA(37%)+VALU(22%) ~= 95% of the
// wall with no pipe >50% -> pipes run back-to-back because all waves are
// phase-locked (identical code, shared release points). Fix: one-time ~960cyc
// s_sleep for waves 4-7 (2nd wave per SIMD) offsets their LDS phase onto the
// other group's MFMA phase; tiny per-tile nudge maintains the offset.
// Math bit-identical to R6 -> absmax 0.
// x [32,256,32,32] f32, codebook [8192,256] f32.
// d2 = (||f||^2 - 2 f.c) + ||c||^2, argmin over 8192 codes, np association.
// f.c = 2^-26 * MFMA(h/m split of 8192*f, 8192*c): products hh+hm+mh.
// Outputs: codes [32,256,32,32] f32 then indices [32,32,32] (as float).

typedef _Float16 v8h __attribute__((ext_vector_type(8)));
typedef float f32x16 __attribute__((ext_vector_type(16)));
typedef unsigned int u32;

#define MFMA16 __builtin_amdgcn_mfma_f32_32x32x16_f16

__device__ __forceinline__ void gll16(const _Float16* g, _Float16* l) {
  __builtin_amdgcn_global_load_lds(
      (const __attribute__((address_space(1))) void*)(const void*)g,
      (__attribute__((address_space(3))) void*)(void*)l, 16, 0, 0);
}

__global__ __launch_bounds__(256) void cnorm_k(const float4* __restrict__ cb4,
                                               float* __restrict__ cn) {
  int lane = threadIdx.x & 63;
  int row = (blockIdx.x << 2) + (threadIdx.x >> 6);
  float4 v = cb4[(size_t)row * 64 + lane];
  float s = v.x * v.x + v.y * v.y + v.z * v.z + v.w * v.w;
#pragma unroll
  for (int off = 32; off > 0; off >>= 1) s += __shfl_xor(s, off, 64);
  if (lane == 0) cn[row] = s;
}

// Pre-split codebook into h/m fp16 planes. Granule g = ct*16+ks = 32 KB laid out
// [w(8)][pl(2)][hi(2)][c64(64)][8]; per-wave chunk = 2048 halves (4 KB).
// value = plane of 8192*cb[ct*512 + w*64 + c64][ks*16 + hi*8 + i].
__global__ __launch_bounds__(256) void split_cb(const float4* __restrict__ cb4,
                                                _Float16* __restrict__ W) {
  const int j = threadIdx.x & 31;
  const int ks = j >> 1, hi = j & 1;
  const int r = (blockIdx.x << 3) + (threadIdx.x >> 5);  // code row 0..8191
  const float4* src = cb4 + (size_t)r * 64 + (ks << 2) + (hi << 1);
  float4 v0 = src[0], v1 = src[1];
  float t[8] = {v0.x, v0.y, v0.z, v0.w, v1.x, v1.y, v1.z, v1.w};
  v8h hv, mv;
#pragma unroll
  for (int i = 0; i < 8; ++i) {
    float vs = t[i] * 8192.f;
    _Float16 h = (_Float16)vs;
    _Float16 m = (_Float16)(vs - (float)h);
    hv[i] = h; mv[i] = m;
  }
  const int wv = (r >> 6) & 7, c64 = r & 63;
  _Float16* base = W + ((size_t)((r >> 9) << 4) + ks) * 16384 + (wv << 11);
  *(v8h*)(base + (hi << 9) + (c64 << 3)) = hv;           // pl=0
  *(v8h*)(base + 1024 + (hi << 9) + (c64 << 3)) = mv;    // pl=1
}

__global__ void __launch_bounds__(512, 1) vq_fast(const float* __restrict__ x,
                                                  const float4* __restrict__ cb4,
                                                  const float* __restrict__ cn,
                                                  const _Float16* __restrict__ W,
                                                  float* __restrict__ out) {
  __shared__ __align__(16) _Float16 F2[2][64][264];   // 67,584 B: -2x splits, padded
  __shared__ __align__(16) _Float16 Bsh[2][16384];    // 65,536 B: dbuf, per-wave chunks
  __shared__ float fnP[64][8];
  __shared__ float fnS[64];
  __shared__ float wredS[8][64];
  __shared__ u32  wredC[8][64];
  __shared__ u32  finS[64];

  const int tid = threadIdx.x;
  const int lane = tid & 63;
  const int w = tid >> 6;
  const int col = lane & 31;
  const int hi = lane >> 5;
  const int b = blockIdx.x >> 4;
  const int h0 = (blockIdx.x & 15) << 1;

  const int chunk = w << 11;                     // wave chunk base (halves)
  const int rb0 = chunk + (hi << 9) + (col << 3);  // bh0 read offset
  // bh1 = rb0+256 ; bm0 = rb0+1024 ; bm1 = rb0+1280

  // ---- prologue: stage tile 0 into this wave's Bsh[0] chunk
  {
    const _Float16* src = W + chunk + (lane << 3);
#pragma unroll
    for (int i = 0; i < 4; ++i) gll16(src + (i << 9), &Bsh[0][chunk + (i << 9)]);
  }

  // ---- stage F splits (scaled by 2^13) + fn partials
  {
    const float* xb = x + ((size_t)b << 18) + (h0 << 5);
    float s = 0.f;
#pragma unroll
    for (int j = 0; j < 4; ++j) {
      v8h hv, mv;
#pragma unroll
      for (int i = 0; i < 8; ++i) {
        const int c = (w << 5) + (j << 3) + i;
        float v = xb[(size_t)c * 1024 + lane];   // coalesced: lane = point
        s += v * v;
        float vs = v * 8192.f;
        _Float16 h = (_Float16)vs;
        _Float16 m = (_Float16)(vs - (float)h);
        hv[i] = h; mv[i] = m;
      }
      *(v8h*)&F2[0][lane][(w << 5) + (j << 3)] = hv;
      *(v8h*)&F2[1][lane][(w << 5) + (j << 3)] = mv;
    }
    fnP[lane][w] = s;
  }
  __syncthreads();   // F2 + fnP visible
  if (tid < 64) {
    float t = 0.f;
#pragma unroll
    for (int j = 0; j < 8; ++j) t += fnP[tid][j];
    fnS[tid] = t;
  }
  __syncthreads();   // fnS visible — last barrier before the final reductions

  // ---- PHASE STAGGER: offset the 2nd wave on each SIMD (waves 4-7, given
  // w -> SIMD w%4 round-robin) by ~960 cyc ≈ half a k-step, so its LDS phase
  // overlaps the other group's MFMA phase instead of colliding with it.
  if (w >= 4) __builtin_amdgcn_s_sleep(15);

  float fnr[32];
#pragma unroll
  for (int sl = 0; sl < 32; ++sl) {
    const int row = ((sl >> 4) << 5) + (sl & 3) + (((sl >> 2) & 3) << 3) + (hi << 2);
    fnr[sl] = fnS[row];
  }

  f32x16 a00, a01, a10, a11;
#pragma unroll
  for (int r = 0; r < 16; ++r) { a00[r] = 0.f; a01[r] = 0.f; a10[r] = 0.f; a11[r] = 0.f; }
  float mn[32];
#pragma unroll
  for (int sl = 0; sl < 32; ++sl) mn[sl] = INFINITY;
  u32 idp[8] = {0, 0, 0, 0, 0, 0, 0, 0};
  float cnv0 = 0.f, cnv1 = 0.f;

  // ---- main loop: 16 code tiles x 16 k-steps; NO barriers, per-wave dbuf
#pragma unroll 1
  for (int ct = 0; ct < 16; ++ct) {
    // maintenance nudge: keep the stagger from collapsing back into lockstep
    if (w >= 4) __builtin_amdgcn_s_sleep(1);
#pragma unroll
    for (int ks = 0; ks < 16; ++ks) {
      const int st = (ct << 4) + ks;
      if (ks == 0) {                       // issued before glls -> drained by wait
        cnv0 = cn[(ct << 9) + (w << 6) + col];
        cnv1 = cn[(ct << 9) + (w << 6) + 32 + col];
      }
      const bool more = (ct < 15) || (ks < 15);
      if (more) {                          // prefetch stage(st+1), stays in flight
        const _Float16* src = W + ((size_t)(st + 1) << 14) + chunk + (lane << 3);
        _Float16* dst = &Bsh[(st + 1) & 1][chunk];
#pragma unroll
        for (int i = 0; i < 4; ++i) gll16(src + (i << 9), dst + (i << 9));
      }
      if (more) asm volatile("s_waitcnt vmcnt(4)" ::: "memory");  // stage(st) done
      else      asm volatile("s_waitcnt vmcnt(0)" ::: "memory");
      __builtin_amdgcn_sched_barrier(0);

      const int ko = (ks << 4) + (hi << 3);
      const v8h ah0 = *(const v8h*)&F2[0][col][ko];
      const v8h ah1 = *(const v8h*)&F2[0][32 + col][ko];
      const v8h am0 = *(const v8h*)&F2[1][col][ko];
      const v8h am1 = *(const v8h*)&F2[1][32 + col][ko];
      const _Float16* Bb = Bsh[st & 1];
      const v8h bh0 = *(const v8h*)&Bb[rb0];
      const v8h bh1 = *(const v8h*)&Bb[rb0 + 256];
      const v8h bm0 = *(const v8h*)&Bb[rb0 + 1024];
      const v8h bm1 = *(const v8h*)&Bb[rb0 + 1280];

      a00 = MFMA16(ah0, bh0, a00, 0, 0, 0);
      a01 = MFMA16(ah0, bh1, a01, 0, 0, 0);
      a10 = MFMA16(ah1, bh0, a10, 0, 0, 0);
      a11 = MFMA16(ah1, bh1, a11, 0, 0, 0);
      a00 = MFMA16(ah0, bm0, a00, 0, 0, 0);
      a01 = MFMA16(ah0, bm1, a01, 0, 0, 0);
      a10 = MFMA16(ah1, bm0, a10, 0, 0, 0);
      a11 = MFMA16(ah1, bm1, a11, 0, 0, 0);
      a00 = MFMA16(am0, bh0, a00, 0, 0, 0);
      a01 = MFMA16(am0, bh1, a01, 0, 0, 0);
      a10 = MFMA16(am1, bh0, a10, 0, 0, 0);
      a11 = MFMA16(am1, bh1, a11, 0, 0, 0);
    }
    // ---- tile epilogue: s = (fn - 2*dot) + cn, running argmin
#pragma unroll
    for (int sl = 0; sl < 32; ++sl) {
      const int Mb = sl >> 4, reg = sl & 15;
      const float base = fnr[sl];
      const u32 sh = (u32)((sl & 3) << 3);
      {
        const float d = (Mb == 0) ? a00[reg] : a10[reg];
        float s = (base + (-0x1p-25f) * d) + cnv0;
        const bool better = s < mn[sl];
        const u32 curv = idp[sl >> 2];
        const u32 upd = (curv & ~(255u << sh)) | (((u32)(ct << 1)) << sh);
        idp[sl >> 2] = better ? upd : curv;
        mn[sl] = better ? s : mn[sl];
      }
      {
        const float d = (Mb == 0) ? a01[reg] : a11[reg];
        float s = (base + (-0x1p-25f) * d) + cnv1;
        const bool better = s < mn[sl];
        const u32 curv = idp[sl >> 2];
        const u32 upd = (curv & ~(255u << sh)) | (((u32)((ct << 1) | 1)) << sh);
        idp[sl >> 2] = better ? upd : curv;
        mn[sl] = better ? s : mn[sl];
      }
    }
#pragma unroll
    for (int r = 0; r < 16; ++r) { a00[r] = 0.f; a01[r] = 0.f; a10[r] = 0.f; a11[r] = 0.f; }
  }

  // ---- final reduction: per-slot butterfly over 32 col-lanes, then cross-wave
#pragma unroll
  for (int sl = 0; sl < 32; ++sl) {
    float v = mn[sl];
    const u32 byte = (idp[sl >> 2] >> ((sl & 3) << 3)) & 255u;
    u32 code = ((byte >> 1) << 9) + ((u32)w << 6) + ((byte & 1) << 5) + (u32)col;
#pragma unroll
    for (int off = 1; off < 32; off <<= 1) {
      float v2 = __shfl_xor(v, off, 64);
      u32 c2 = (u32)__shfl_xor((int)code, off, 64);
      if (v2 < v || (v2 == v && c2 < code)) { v = v2; code = c2; }
    }
    if (col == 0) {
      const int row = ((sl >> 4) << 5) + (sl & 3) + (((sl >> 2) & 3) << 3) + (hi << 2);
      wredS[w][row] = v; wredC[w][row] = code;
    }
  }
  __syncthreads();
  if (tid < 64) {
    float bv = wredS[0][tid]; u32 bc = wredC[0][tid];
#pragma unroll
    for (int j = 1; j < 8; ++j) {
      float vv = wredS[j][tid]; u32 cc = wredC[j][tid];
      if (vv < bv || (vv == bv && cc < bc)) { bv = vv; bc = cc; }
    }
    finS[tid] = bc;
    out[(size_t)8388608 + ((size_t)b << 10) + (h0 << 5) + tid] = (float)bc;
  }
  __syncthreads();

  // ---- codes gather: out[b,c,h,w] = codebook[idx][c]
  {
    const int pt = tid & 63, cg = tid >> 6;
    const u32 code = finS[pt];
    const float4* cbr = cb4 + ((size_t)code << 6);
    const size_t obase = ((size_t)b << 18) + (h0 << 5) + pt;
#pragma unroll
    for (int cc = 0; cc < 8; ++cc) {
      const int c4 = (cc << 3) + cg;
      float4 vv = cbr[c4];
      out[obase + (size_t)((c4 << 2) + 0) * 1024] = vv.x;
      out[obase + (size_t)((c4 << 2) + 1) * 1024] = vv.y;
      out[obase + (size_t)((c4 << 2) + 2) * 1024] = vv.z;
      out[obase + (size_t)((c4 << 2) + 3) * 1024] = vv.w;
    }
  }
}

// ---------------- fallback (round-3 kernel, used only if ws too small) -------
__global__ void __launch_bounds__(512, 2) vq_fb(const float* __restrict__ x,
                                                const float4* __restrict__ cb4,
                                                const float* __restrict__ cn,
                                                float* __restrict__ out) {
  __shared__ __align__(16) _Float16 F2[2][64][264];
  __shared__ __align__(16) _Float16 Bsh[512][72];
  __shared__ float fnP[64][8];
  __shared__ float fnS[64];
  __shared__ float wredS[8][64];
  __shared__ u32  wredC[8][64];
  __shared__ u32  finS[64];

  const int tid = threadIdx.x;
  const int lane = tid & 63;
  const int w = tid >> 6;
  const int col = lane & 31;
  const int hi = lane >> 5;
  const int b = blockIdx.x >> 4;
  const int h0 = (blockIdx.x & 15) << 1;

  float4 rg[8];
  {
    const float4* src = cb4 + ((size_t)tid << 6);
#pragma unroll
    for (int j = 0; j < 8; ++j) rg[j] = src[j];
  }
  {
    const float* xb = x + ((size_t)b << 18) + (h0 << 5);
    float s = 0.f;
#pragma unroll
    for (int j = 0; j < 4; ++j) {
      v8h hv, mv;
#pragma unroll
      for (int i = 0; i < 8; ++i) {
        const int c = (w << 5) + (j << 3) + i;
        float v = xb[(size_t)c * 1024 + lane];
        s += v * v;
        float vs = v * 8192.f;
        _Float16 h = (_Float16)vs;
        _Float16 m = (_Float16)(vs - (float)h);
        hv[i] = h; mv[i] = m;
      }
      *(v8h*)&F2[0][lane][(w << 5) + (j << 3)] = hv;
      *(v8h*)&F2[1][lane][(w << 5) + (j << 3)] = mv;
    }
    fnP[lane][w] = s;
  }
  __syncthreads();
  if (tid < 64) {
    float t = 0.f;
#pragma unroll
    for (int j = 0; j < 8; ++j) t += fnP[tid][j];
    fnS[tid] = t;
  }
  {
#pragma unroll
    for (int j = 0; j < 4; ++j) {
      float t0[8] = {rg[2*j].x, rg[2*j].y, rg[2*j].z, rg[2*j].w,
                     rg[2*j+1].x, rg[2*j+1].y, rg[2*j+1].z, rg[2*j+1].w};
      v8h hv, mv;
#pragma unroll
      for (int i = 0; i < 8; ++i) {
        float vs = t0[i] * 8192.f;
        _Float16 h = (_Float16)vs;
        _Float16 m = (_Float16)(vs - (float)h);
        hv[i] = h; mv[i] = m;
      }
      *(v8h*)&Bsh[tid][(j << 3)] = hv;
      *(v8h*)&Bsh[tid][32 + (j << 3)] = mv;
    }
  }
  __syncthreads();

  float fnr[32];
#pragma unroll
  for (int sl = 0; sl < 32; ++sl) {
    const int row = ((sl >> 4) << 5) + (sl & 3) + (((sl >> 2) & 3) << 3) + (hi << 2);
    fnr[sl] = fnS[row];
  }

  f32x16 acc[2][2];
#pragma unroll
  for (int r = 0; r < 16; ++r) {
    acc[0][0][r] = 0.f; acc[0][1][r] = 0.f; acc[1][0][r] = 0.f; acc[1][1][r] = 0.f;
  }
  float mn[32];
#pragma unroll
  for (int sl = 0; sl < 32; ++sl) mn[sl] = INFINITY;
  u32 idp[8] = {0, 0, 0, 0, 0, 0, 0, 0};
  float cnv0 = 0.f, cnv1 = 0.f;

  for (int st = 0; st < 128; ++st) {
    const int ks = st & 7, ct = st >> 3;
    if (st < 127) {
      const int tn = st + 1;
      const float4* src = cb4 + ((size_t)((((tn >> 3) << 9) + tid)) << 6) + ((tn & 7) << 3);
#pragma unroll
      for (int j = 0; j < 8; ++j) rg[j] = src[j];
    }
    if (ks == 0) {
      cnv0 = cn[(ct << 9) + (w << 6) + col];
      cnv1 = cn[(ct << 9) + (w << 6) + 32 + col];
    }
    const int kb = ks << 5;
#pragma unroll
    for (int kh = 0; kh < 2; ++kh) {
      const int ko = kb + (kh << 4) + (hi << 3);
      const v8h ah0 = *(const v8h*)&F2[0][col][ko];
      const v8h ah1 = *(const v8h*)&F2[0][32 + col][ko];
      const v8h am0 = *(const v8h*)&F2[1][col][ko];
      const v8h am1 = *(const v8h*)&F2[1][32 + col][ko];
      const int bo = (kh << 4) + (hi << 3);
      const v8h bh0 = *(const v8h*)&Bsh[(w << 6) + col][bo];
      const v8h bh1 = *(const v8h*)&Bsh[(w << 6) + 32 + col][bo];
      const v8h bm0 = *(const v8h*)&Bsh[(w << 6) + col][32 + bo];
      const v8h bm1 = *(const v8h*)&Bsh[(w << 6) + 32 + col][32 + bo];
      acc[0][0] = MFMA16(ah0, bh0, acc[0][0], 0, 0, 0);
      acc[0][0] = MFMA16(ah0, bm0, acc[0][0], 0, 0, 0);
      acc[0][0] = MFMA16(am0, bh0, acc[0][0], 0, 0, 0);
      acc[0][1] = MFMA16(ah0, bh1, acc[0][1], 0, 0, 0);
      acc[0][1] = MFMA16(ah0, bm1, acc[0][1], 0, 0, 0);
      acc[0][1] = MFMA16(am0, bh1, acc[0][1], 0, 0, 0);
      acc[1][0] = MFMA16(ah1, bh0, acc[1][0], 0, 0, 0);
      acc[1][0] = MFMA16(ah1, bm0, acc[1][0], 0, 0, 0);
      acc[1][0] = MFMA16(am1, bh0, acc[1][0], 0, 0, 0);
      acc[1][1] = MFMA16(ah1, bh1, acc[1][1], 0, 0, 0);
      acc[1][1] = MFMA16(ah1, bm1, acc[1][1], 0, 0, 0);
      acc[1][1] = MFMA16(am1, bh1, acc[1][1], 0, 0, 0);
    }
    if (ks == 7) {
#pragma unroll
      for (int sl = 0; sl < 32; ++sl) {
        const int Mb = sl >> 4, reg = sl & 15;
        const float base = fnr[sl];
        const u32 sh = (u32)((sl & 3) << 3);
        {
          float s = (base + (-0x1p-25f) * acc[Mb][0][reg]) + cnv0;
          const bool better = s < mn[sl];
          const u32 curv = idp[sl >> 2];
          const u32 upd = (curv & ~(255u << sh)) | (((u32)(ct << 1)) << sh);
          idp[sl >> 2] = better ? upd : curv;
          mn[sl] = better ? s : mn[sl];
        }
        {
          float s = (base + (-0x1p-25f) * acc[Mb][1][reg]) + cnv1;
          const bool better = s < mn[sl];
          const u32 curv = idp[sl >> 2];
          const u32 upd = (curv & ~(255u << sh)) | (((u32)((ct << 1) | 1)) << sh);
          idp[sl >> 2] = better ? upd : curv;
          mn[sl] = better ? s : mn[sl];
        }
      }
#pragma unroll
      for (int r = 0; r < 16; ++r) {
        acc[0][0][r] = 0.f; acc[0][1][r] = 0.f; acc[1][0][r] = 0.f; acc[1][1][r] = 0.f;
      }
    }
    v8h cr[8];
    if (st < 127) {
#pragma unroll
      for (int j = 0; j < 4; ++j) {
        float t0[8] = {rg[2*j].x, rg[2*j].y, rg[2*j].z, rg[2*j].w,
                       rg[2*j+1].x, rg[2*j+1].y, rg[2*j+1].z, rg[2*j+1].w};
#pragma unroll
        for (int i = 0; i < 8; ++i) {
          float vs = t0[i] * 8192.f;
          _Float16 h = (_Float16)vs;
          _Float16 m = (_Float16)(vs - (float)h);
          cr[j][i] = h; cr[4 + j][i] = m;
        }
      }
    }
    __syncthreads();
    if (st < 127) {
#pragma unroll
      for (int j = 0; j < 4; ++j) {
        *(v8h*)&Bsh[tid][(j << 3)] = cr[j];
        *(v8h*)&Bsh[tid][32 + (j << 3)] = cr[4 + j];
      }
    }
    __syncthreads();
  }

#pragma unroll
  for (int sl = 0; sl < 32; ++sl) {
    float v = mn[sl];
    const u32 byte = (idp[sl >> 2] >> ((sl & 3) << 3)) & 255u;
    u32 code = ((byte >> 1) << 9) + ((u32)w << 6) + ((byte & 1) << 5) + (u32)col;
#pragma unroll
    for (int off = 1; off < 32; off <<= 1) {
      float v2 = __shfl_xor(v, off, 64);
      u32 c2 = (u32)__shfl_xor((int)code, off, 64);
      if (v2 < v || (v2 == v && c2 < code)) { v = v2; code = c2; }
    }
    if (col == 0) {
      const int row = ((sl >> 4) << 5) + (sl & 3) + (((sl >> 2) & 3) << 3) + (hi << 2);
      wredS[w][row] = v; wredC[w][row] = code;
    }
  }
  __syncthreads();
  if (tid < 64) {
    float bv = wredS[0][tid]; u32 bc = wredC[0][tid];
#pragma unroll
    for (int j = 1; j < 8; ++j) {
      float vv = wredS[j][tid]; u32 cc = wredC[j][tid];
      if (vv < bv || (vv == bv && cc < bc)) { bv = vv; bc = cc; }
    }
    finS[tid] = bc;
    out[(size_t)8388608 + ((size_t)b << 10) + (h0 << 5) + tid] = (float)bc;
  }
  __syncthreads();
  {
    const int pt = tid & 63, cg = tid >> 6;
    const u32 code = finS[pt];
    const float4* cbr = cb4 + ((size_t)code << 6);
    const size_t obase = ((size_t)b << 18) + (h0 << 5) + pt;
#pragma unroll
    for (int cc = 0; cc < 8; ++cc) {
      const int c4 = (cc << 3) + cg;
      float4 vv = cbr[c4];
      out[obase + (size_t)((c4 << 2) + 0) * 1024] = vv.x;
      out[obase + (size_t)((c4 << 2) + 1) * 1024] = vv.y;
      out[obase + (size_t)((c4 << 2) + 2) * 1024] = vv.z;
      out[obase + (size_t)((c4 << 2) + 3) * 1024] = vv.w;
    }
  }
}

extern "C" void kernel_launch(void* const* d_in, const int* in_sizes, int n_in,
                              void* d_out, int out_size, void* d_ws, size_t ws_size,
                              hipStream_t stream) {
  const float* x = (const float*)d_in[0];
  const float* cb = (const float*)d_in[1];
  float* out = (float*)d_out;
  float* cnorm = (float*)d_ws;  // 8192 floats at ws[0:32KB)

  cnorm_k<<<2048, 256, 0, stream>>>((const float4*)cb, cnorm);
  if (ws_size >= (size_t)32768 + (size_t)8388608) {
    _Float16* W = (_Float16*)((char*)d_ws + 32768);  // 8 MB split-permuted planes
    split_cb<<<1024, 256, 0, stream>>>((const float4*)cb, W);
    vq_fast<<<512, 512, 0, stream>>>(x, (const float4*)cb, cnorm, W, out);
  } else {
    vq_fb<<<512, 512, 0, stream>>>(x, (const float4*)cb, cnorm, out);
  }
}

// Round 14
// 440.770 us; speedup vs baseline: 1.9124x; 1.0022x over previous
//
#include <hip/hip_runtime.h>
#include <math.h>

// VQ via split-fp16 MFMA emulation of fp32 GEMM.
// Round 14: K=32 steps — consume TWO granules (64 KB single-buffered Bsh) per
// step, 24 MFMA per wave between wait-points (was 12), 128 steps (was 256).
// Order per step: 16 B ds_reads -> lgkmcnt(0) -> 8 glls (overwrite) ->
// A-reads + 24 MFMA -> vmcnt(0). Tests whether the ~1300cyc/step residual is
// per-wait-point overhead. MFMA per-chain order (ks asc; hh,hm,mh) identical
// to R6 -> bit-exact accumulators -> absmax 0.
// x [32,256,32,32] f32, codebook [8192,256] f32.
// d2 = (||f||^2 - 2 f.c) + ||c||^2, argmin over 8192 codes, np association.
// f.c = 2^-26 * MFMA(h/m split of 8192*f, 8192*c): products hh+hm+mh.
// Outputs: codes [32,256,32,32] f32 then indices [32,32,32] (as float).

typedef _Float16 v8h __attribute__((ext_vector_type(8)));
typedef float f32x16 __attribute__((ext_vector_type(16)));
typedef unsigned int u32;

#define MFMA16 __builtin_amdgcn_mfma_f32_32x32x16_f16

__device__ __forceinline__ void gll16(const _Float16* g, _Float16* l) {
  __builtin_amdgcn_global_load_lds(
      (const __attribute__((address_space(1))) void*)(const void*)g,
      (__attribute__((address_space(3))) void*)(void*)l, 16, 0, 0);
}

__global__ __launch_bounds__(256) void cnorm_k(const float4* __restrict__ cb4,
                                               float* __restrict__ cn) {
  int lane = threadIdx.x & 63;
  int row = (blockIdx.x << 2) + (threadIdx.x >> 6);
  float4 v = cb4[(size_t)row * 64 + lane];
  float s = v.x * v.x + v.y * v.y + v.z * v.z + v.w * v.w;
#pragma unroll
  for (int off = 32; off > 0; off >>= 1) s += __shfl_xor(s, off, 64);
  if (lane == 0) cn[row] = s;
}

// Pre-split codebook into h/m fp16 planes. Granule g = ct*16+ks = 32 KB laid out
// [w(8)][pl(2)][hi(2)][c64(64)][8]; per-wave chunk = 2048 halves (4 KB).
// value = plane of 8192*cb[ct*512 + w*64 + c64][ks*16 + hi*8 + i].
__global__ __launch_bounds__(256) void split_cb(const float4* __restrict__ cb4,
                                                _Float16* __restrict__ W) {
  const int j = threadIdx.x & 31;
  const int ks = j >> 1, hi = j & 1;
  const int r = (blockIdx.x << 3) + (threadIdx.x >> 5);  // code row 0..8191
  const float4* src = cb4 + (size_t)r * 64 + (ks << 2) + (hi << 1);
  float4 v0 = src[0], v1 = src[1];
  float t[8] = {v0.x, v0.y, v0.z, v0.w, v1.x, v1.y, v1.z, v1.w};
  v8h hv, mv;
#pragma unroll
  for (int i = 0; i < 8; ++i) {
    float vs = t[i] * 8192.f;
    _Float16 h = (_Float16)vs;
    _Float16 m = (_Float16)(vs - (float)h);
    hv[i] = h; mv[i] = m;
  }
  const int wv = (r >> 6) & 7, c64 = r & 63;
  _Float16* base = W + ((size_t)((r >> 9) << 4) + ks) * 16384 + (wv << 11);
  *(v8h*)(base + (hi << 9) + (c64 << 3)) = hv;           // pl=0
  *(v8h*)(base + 1024 + (hi << 9) + (c64 << 3)) = mv;    // pl=1
}

__global__ void __launch_bounds__(512, 1) vq_fast(const float* __restrict__ x,
                                                  const float4* __restrict__ cb4,
                                                  const float* __restrict__ cn,
                                                  const _Float16* __restrict__ W,
                                                  float* __restrict__ out) {
  __shared__ __align__(16) _Float16 F2[2][64][264];   // 67,584 B: -2x splits, padded
  __shared__ __align__(16) _Float16 Bsh[32768];       // 65,536 B: TWO granules, single-buf
  __shared__ float fnP[64][8];
  __shared__ float fnS[64];
  __shared__ float wredS[8][64];
  __shared__ u32  wredC[8][64];
  __shared__ u32  finS[64];

  const int tid = threadIdx.x;
  const int lane = tid & 63;
  const int w = tid >> 6;
  const int col = lane & 31;
  const int hi = lane >> 5;
  const int b = blockIdx.x >> 4;
  const int h0 = (blockIdx.x & 15) << 1;

  const int chunk = w << 11;                       // wave chunk base within a granule
  const int rb0 = chunk + (hi << 9) + (col << 3);  // bh0; +256=bh1, +1024=bm0, +1280=bm1
  // granule-odd copies live at +16384

  // ---- prologue: stage granules 0,1 (drained by the barrier below)
  {
    const _Float16* s0 = W + chunk + (lane << 3);
#pragma unroll
    for (int i = 0; i < 4; ++i) gll16(s0 + (i << 9), &Bsh[chunk + (i << 9)]);
#pragma unroll
    for (int i = 0; i < 4; ++i) gll16(s0 + 16384 + (i << 9), &Bsh[16384 + chunk + (i << 9)]);
  }

  // ---- stage F splits (scaled by 2^13) + fn partials
  {
    const float* xb = x + ((size_t)b << 18) + (h0 << 5);
    float s = 0.f;
#pragma unroll
    for (int j = 0; j < 4; ++j) {
      v8h hv, mv;
#pragma unroll
      for (int i = 0; i < 8; ++i) {
        const int c = (w << 5) + (j << 3) + i;
        float v = xb[(size_t)c * 1024 + lane];   // coalesced: lane = point
        s += v * v;
        float vs = v * 8192.f;
        _Float16 h = (_Float16)vs;
        _Float16 m = (_Float16)(vs - (float)h);
        hv[i] = h; mv[i] = m;
      }
      *(v8h*)&F2[0][lane][(w << 5) + (j << 3)] = hv;
      *(v8h*)&F2[1][lane][(w << 5) + (j << 3)] = mv;
    }
    fnP[lane][w] = s;
  }
  __syncthreads();   // F2 + fnP visible; prologue glls drained
  if (tid < 64) {
    float t = 0.f;
#pragma unroll
    for (int j = 0; j < 8; ++j) t += fnP[tid][j];
    fnS[tid] = t;
  }
  __syncthreads();   // fnS visible — last barrier before the final reductions

  float fnr[32];
#pragma unroll
  for (int sl = 0; sl < 32; ++sl) {
    const int row = ((sl >> 4) << 5) + (sl & 3) + (((sl >> 2) & 3) << 3) + (hi << 2);
    fnr[sl] = fnS[row];
  }

  f32x16 a00, a01, a10, a11;
#pragma unroll
  for (int r = 0; r < 16; ++r) { a00[r] = 0.f; a01[r] = 0.f; a10[r] = 0.f; a11[r] = 0.f; }
  float mn[32];
#pragma unroll
  for (int sl = 0; sl < 32; ++sl) mn[sl] = INFINITY;
  u32 idp[8] = {0, 0, 0, 0, 0, 0, 0, 0};
  float cnv0 = 0.f, cnv1 = 0.f;

  // ---- main loop: 16 code tiles x 8 K=32-steps; single-buffer, 1 wait-pair/step
#pragma unroll 1
  for (int ct = 0; ct < 16; ++ct) {
#pragma unroll
    for (int u = 0; u < 8; ++u) {
      const int t = (ct << 3) + u;        // step 0..127 (granules 2t, 2t+1)
      if (u == 0) {                       // drained by the step's vmcnt(0)
        cnv0 = cn[(ct << 9) + (w << 6) + col];
        cnv1 = cn[(ct << 9) + (w << 6) + 32 + col];
      }
      // (1) read ALL B frags for both granules (Bsh about to be overwritten)
      const v8h b0h0 = *(const v8h*)&Bsh[rb0];
      const v8h b0h1 = *(const v8h*)&Bsh[rb0 + 256];
      const v8h b0m0 = *(const v8h*)&Bsh[rb0 + 1024];
      const v8h b0m1 = *(const v8h*)&Bsh[rb0 + 1280];
      const v8h b1h0 = *(const v8h*)&Bsh[16384 + rb0];
      const v8h b1h1 = *(const v8h*)&Bsh[16384 + rb0 + 256];
      const v8h b1m0 = *(const v8h*)&Bsh[16384 + rb0 + 1024];
      const v8h b1m1 = *(const v8h*)&Bsh[16384 + rb0 + 1280];
      asm volatile("s_waitcnt lgkmcnt(0)" ::: "memory");  // B in regs
      __builtin_amdgcn_sched_barrier(0);
      // (2) stage granules 2t+2, 2t+3 into the just-read buffer
      if (t < 127) {
        const _Float16* gsrc = W + ((size_t)(2 * t + 2) << 14) + chunk + (lane << 3);
#pragma unroll
        for (int i = 0; i < 4; ++i) gll16(gsrc + (i << 9), &Bsh[chunk + (i << 9)]);
#pragma unroll
        for (int i = 0; i < 4; ++i)
          gll16(gsrc + 16384 + (i << 9), &Bsh[16384 + chunk + (i << 9)]);
      }
      // (3) A frags (F2 not overwritten — compiler inserts lgkm) + 24 MFMA.
      // Per-chain order: ks even {hh,hm,mh} then ks odd {hh,hm,mh} == R6 exact.
      {
        const int ko = ((u << 1) << 4) + (hi << 3);       // ks = 2u
        const v8h ah0 = *(const v8h*)&F2[0][col][ko];
        const v8h ah1 = *(const v8h*)&F2[0][32 + col][ko];
        const v8h am0 = *(const v8h*)&F2[1][col][ko];
        const v8h am1 = *(const v8h*)&F2[1][32 + col][ko];
        a00 = MFMA16(ah0, b0h0, a00, 0, 0, 0);
        a01 = MFMA16(ah0, b0h1, a01, 0, 0, 0);
        a10 = MFMA16(ah1, b0h0, a10, 0, 0, 0);
        a11 = MFMA16(ah1, b0h1, a11, 0, 0, 0);
        a00 = MFMA16(ah0, b0m0, a00, 0, 0, 0);
        a01 = MFMA16(ah0, b0m1, a01, 0, 0, 0);
        a10 = MFMA16(ah1, b0m0, a10, 0, 0, 0);
        a11 = MFMA16(ah1, b0m1, a11, 0, 0, 0);
        a00 = MFMA16(am0, b0h0, a00, 0, 0, 0);
        a01 = MFMA16(am0, b0h1, a01, 0, 0, 0);
        a10 = MFMA16(am1, b0h0, a10, 0, 0, 0);
        a11 = MFMA16(am1, b0h1, a11, 0, 0, 0);
      }
      {
        const int ko = (((u << 1) + 1) << 4) + (hi << 3); // ks = 2u+1
        const v8h ah0 = *(const v8h*)&F2[0][col][ko];
        const v8h ah1 = *(const v8h*)&F2[0][32 + col][ko];
        const v8h am0 = *(const v8h*)&F2[1][col][ko];
        const v8h am1 = *(const v8h*)&F2[1][32 + col][ko];
        a00 = MFMA16(ah0, b1h0, a00, 0, 0, 0);
        a01 = MFMA16(ah0, b1h1, a01, 0, 0, 0);
        a10 = MFMA16(ah1, b1h0, a10, 0, 0, 0);
        a11 = MFMA16(ah1, b1h1, a11, 0, 0, 0);
        a00 = MFMA16(ah0, b1m0, a00, 0, 0, 0);
        a01 = MFMA16(ah0, b1m1, a01, 0, 0, 0);
        a10 = MFMA16(ah1, b1m0, a10, 0, 0, 0);
        a11 = MFMA16(ah1, b1m1, a11, 0, 0, 0);
        a00 = MFMA16(am0, b1h0, a00, 0, 0, 0);
        a01 = MFMA16(am0, b1h1, a01, 0, 0, 0);
        a10 = MFMA16(am1, b1h0, a10, 0, 0, 0);
        a11 = MFMA16(am1, b1h1, a11, 0, 0, 0);
      }
      // (4) next granule pair landed
      asm volatile("s_waitcnt vmcnt(0)" ::: "memory");
      __builtin_amdgcn_sched_barrier(0);
    }
    // ---- tile epilogue: s = (fn - 2*dot) + cn, running argmin
#pragma unroll
    for (int sl = 0; sl < 32; ++sl) {
      const int Mb = sl >> 4, reg = sl & 15;
      const float base = fnr[sl];
      const u32 sh = (u32)((sl & 3) << 3);
      {
        const float d = (Mb == 0) ? a00[reg] : a10[reg];
        float s = (base + (-0x1p-25f) * d) + cnv0;
        const bool better = s < mn[sl];
        const u32 curv = idp[sl >> 2];
        const u32 upd = (curv & ~(255u << sh)) | (((u32)(ct << 1)) << sh);
        idp[sl >> 2] = better ? upd : curv;
        mn[sl] = better ? s : mn[sl];
      }
      {
        const float d = (Mb == 0) ? a01[reg] : a11[reg];
        float s = (base + (-0x1p-25f) * d) + cnv1;
        const bool better = s < mn[sl];
        const u32 curv = idp[sl >> 2];
        const u32 upd = (curv & ~(255u << sh)) | (((u32)((ct << 1) | 1)) << sh);
        idp[sl >> 2] = better ? upd : curv;
        mn[sl] = better ? s : mn[sl];
      }
    }
#pragma unroll
    for (int r = 0; r < 16; ++r) { a00[r] = 0.f; a01[r] = 0.f; a10[r] = 0.f; a11[r] = 0.f; }
  }

  // ---- final reduction: per-slot butterfly over 32 col-lanes, then cross-wave
#pragma unroll
  for (int sl = 0; sl < 32; ++sl) {
    float v = mn[sl];
    const u32 byte = (idp[sl >> 2] >> ((sl & 3) << 3)) & 255u;
    u32 code = ((byte >> 1) << 9) + ((u32)w << 6) + ((byte & 1) << 5) + (u32)col;
#pragma unroll
    for (int off = 1; off < 32; off <<= 1) {
      float v2 = __shfl_xor(v, off, 64);
      u32 c2 = (u32)__shfl_xor((int)code, off, 64);
      if (v2 < v || (v2 == v && c2 < code)) { v = v2; code = c2; }
    }
    if (col == 0) {
      const int row = ((sl >> 4) << 5) + (sl & 3) + (((sl >> 2) & 3) << 3) + (hi << 2);
      wredS[w][row] = v; wredC[w][row] = code;
    }
  }
  __syncthreads();
  if (tid < 64) {
    float bv = wredS[0][tid]; u32 bc = wredC[0][tid];
#pragma unroll
    for (int j = 1; j < 8; ++j) {
      float vv = wredS[j][tid]; u32 cc = wredC[j][tid];
      if (vv < bv || (vv == bv && cc < bc)) { bv = vv; bc = cc; }
    }
    finS[tid] = bc;
    out[(size_t)8388608 + ((size_t)b << 10) + (h0 << 5) + tid] = (float)bc;
  }
  __syncthreads();

  // ---- codes gather: out[b,c,h,w] = codebook[idx][c]
  {
    const int pt = tid & 63, cg = tid >> 6;
    const u32 code = finS[pt];
    const float4* cbr = cb4 + ((size_t)code << 6);
    const size_t obase = ((size_t)b << 18) + (h0 << 5) + pt;
#pragma unroll
    for (int cc = 0; cc < 8; ++cc) {
      const int c4 = (cc << 3) + cg;
      float4 vv = cbr[c4];
      out[obase + (size_t)((c4 << 2) + 0) * 1024] = vv.x;
      out[obase + (size_t)((c4 << 2) + 1) * 1024] = vv.y;
      out[obase + (size_t)((c4 << 2) + 2) * 1024] = vv.z;
      out[obase + (size_t)((c4 << 2) + 3) * 1024] = vv.w;
    }
  }
}

// ---------------- fallback (round-3 kernel, used only if ws too small) -------
__global__ void __launch_bounds__(512, 2) vq_fb(const float* __restrict__ x,
                                                const float4* __restrict__ cb4,
                                                const float* __restrict__ cn,
                                                float* __restrict__ out) {
  __shared__ __align__(16) _Float16 F2[2][64][264];
  __shared__ __align__(16) _Float16 Bsh[512][72];
  __shared__ float fnP[64][8];
  __shared__ float fnS[64];
  __shared__ float wredS[8][64];
  __shared__ u32  wredC[8][64];
  __shared__ u32  finS[64];

  const int tid = threadIdx.x;
  const int lane = tid & 63;
  const int w = tid >> 6;
  const int col = lane & 31;
  const int hi = lane >> 5;
  const int b = blockIdx.x >> 4;
  const int h0 = (blockIdx.x & 15) << 1;

  float4 rg[8];
  {
    const float4* src = cb4 + ((size_t)tid << 6);
#pragma unroll
    for (int j = 0; j < 8; ++j) rg[j] = src[j];
  }
  {
    const float* xb = x + ((size_t)b << 18) + (h0 << 5);
    float s = 0.f;
#pragma unroll
    for (int j = 0; j < 4; ++j) {
      v8h hv, mv;
#pragma unroll
      for (int i = 0; i < 8; ++i) {
        const int c = (w << 5) + (j << 3) + i;
        float v = xb[(size_t)c * 1024 + lane];
        s += v * v;
        float vs = v * 8192.f;
        _Float16 h = (_Float16)vs;
        _Float16 m = (_Float16)(vs - (float)h);
        hv[i] = h; mv[i] = m;
      }
      *(v8h*)&F2[0][lane][(w << 5) + (j << 3)] = hv;
      *(v8h*)&F2[1][lane][(w << 5) + (j << 3)] = mv;
    }
    fnP[lane][w] = s;
  }
  __syncthreads();
  if (tid < 64) {
    float t = 0.f;
#pragma unroll
    for (int j = 0; j < 8; ++j) t += fnP[tid][j];
    fnS[tid] = t;
  }
  {
#pragma unroll
    for (int j = 0; j < 4; ++j) {
      float t0[8] = {rg[2*j].x, rg[2*j].y, rg[2*j].z, rg[2*j].w,
                     rg[2*j+1].x, rg[2*j+1].y, rg[2*j+1].z, rg[2*j+1].w};
      v8h hv, mv;
#pragma unroll
      for (int i = 0; i < 8; ++i) {
        float vs = t0[i] * 8192.f;
        _Float16 h = (_Float16)vs;
        _Float16 m = (_Float16)(vs - (float)h);
        hv[i] = h; mv[i] = m;
      }
      *(v8h*)&Bsh[tid][(j << 3)] = hv;
      *(v8h*)&Bsh[tid][32 + (j << 3)] = mv;
    }
  }
  __syncthreads();

  float fnr[32];
#pragma unroll
  for (int sl = 0; sl < 32; ++sl) {
    const int row = ((sl >> 4) << 5) + (sl & 3) + (((sl >> 2) & 3) << 3) + (hi << 2);
    fnr[sl] = fnS[row];
  }

  f32x16 acc[2][2];
#pragma unroll
  for (int r = 0; r < 16; ++r) {
    acc[0][0][r] = 0.f; acc[0][1][r] = 0.f; acc[1][0][r] = 0.f; acc[1][1][r] = 0.f;
  }
  float mn[32];
#pragma unroll
  for (int sl = 0; sl < 32; ++sl) mn[sl] = INFINITY;
  u32 idp[8] = {0, 0, 0, 0, 0, 0, 0, 0};
  float cnv0 = 0.f, cnv1 = 0.f;

  for (int st = 0; st < 128; ++st) {
    const int ks = st & 7, ct = st >> 3;
    if (st < 127) {
      const int tn = st + 1;
      const float4* src = cb4 + ((size_t)((((tn >> 3) << 9) + tid)) << 6) + ((tn & 7) << 3);
#pragma unroll
      for (int j = 0; j < 8; ++j) rg[j] = src[j];
    }
    if (ks == 0) {
      cnv0 = cn[(ct << 9) + (w << 6) + col];
      cnv1 = cn[(ct << 9) + (w << 6) + 32 + col];
    }
    const int kb = ks << 5;
#pragma unroll
    for (int kh = 0; kh < 2; ++kh) {
      const int ko = kb + (kh << 4) + (hi << 3);
      const v8h ah0 = *(const v8h*)&F2[0][col][ko];
      const v8h ah1 = *(const v8h*)&F2[0][32 + col][ko];
      const v8h am0 = *(const v8h*)&F2[1][col][ko];
      const v8h am1 = *(const v8h*)&F2[1][32 + col][ko];
      const int bo = (kh << 4) + (hi << 3);
      const v8h bh0 = *(const v8h*)&Bsh[(w << 6) + col][bo];
      const v8h bh1 = *(const v8h*)&Bsh[(w << 6) + 32 + col][bo];
      const v8h bm0 = *(const v8h*)&Bsh[(w << 6) + col][32 + bo];
      const v8h bm1 = *(const v8h*)&Bsh[(w << 6) + 32 + col][32 + bo];
      acc[0][0] = MFMA16(ah0, bh0, acc[0][0], 0, 0, 0);
      acc[0][0] = MFMA16(ah0, bm0, acc[0][0], 0, 0, 0);
      acc[0][0] = MFMA16(am0, bh0, acc[0][0], 0, 0, 0);
      acc[0][1] = MFMA16(ah0, bh1, acc[0][1], 0, 0, 0);
      acc[0][1] = MFMA16(ah0, bm1, acc[0][1], 0, 0, 0);
      acc[0][1] = MFMA16(am0, bh1, acc[0][1], 0, 0, 0);
      acc[1][0] = MFMA16(ah1, bh0, acc[1][0], 0, 0, 0);
      acc[1][0] = MFMA16(ah1, bm0, acc[1][0], 0, 0, 0);
      acc[1][0] = MFMA16(am1, bh0, acc[1][0], 0, 0, 0);
      acc[1][1] = MFMA16(ah1, bh1, acc[1][1], 0, 0, 0);
      acc[1][1] = MFMA16(ah1, bm1, acc[1][1], 0, 0, 0);
      acc[1][1] = MFMA16(am1, bh1, acc[1][1], 0, 0, 0);
    }
    if (ks == 7) {
#pragma unroll
      for (int sl = 0; sl < 32; ++sl) {
        const int Mb = sl >> 4, reg = sl & 15;
        const float base = fnr[sl];
        const u32 sh = (u32)((sl & 3) << 3);
        {
          float s = (base + (-0x1p-25f) * acc[Mb][0][reg]) + cnv0;
          const bool better = s < mn[sl];
          const u32 curv = idp[sl >> 2];
          const u32 upd = (curv & ~(255u << sh)) | (((u32)(ct << 1)) << sh);
          idp[sl >> 2] = better ? upd : curv;
          mn[sl] = better ? s : mn[sl];
        }
        {
          float s = (base + (-0x1p-25f) * acc[Mb][1][reg]) + cnv1;
          const bool better = s < mn[sl];
          const u32 curv = idp[sl >> 2];
          const u32 upd = (curv & ~(255u << sh)) | (((u32)((ct << 1) | 1)) << sh);
          idp[sl >> 2] = better ? upd : curv;
          mn[sl] = better ? s : mn[sl];
        }
      }
#pragma unroll
      for (int r = 0; r < 16; ++r) {
        acc[0][0][r] = 0.f; acc[0][1][r] = 0.f; acc[1][0][r] = 0.f; acc[1][1][r] = 0.f;
      }
    }
    v8h cr[8];
    if (st < 127) {
#pragma unroll
      for (int j = 0; j < 4; ++j) {
        float t0[8] = {rg[2*j].x, rg[2*j].y, rg[2*j].z, rg[2*j].w,
                       rg[2*j+1].x, rg[2*j+1].y, rg[2*j+1].z, rg[2*j+1].w};
#pragma unroll
        for (int i = 0; i < 8; ++i) {
          float vs = t0[i] * 8192.f;
          _Float16 h = (_Float16)vs;
          _Float16 m = (_Float16)(vs - (float)h);
          cr[j][i] = h; cr[4 + j][i] = m;
        }
      }
    }
    __syncthreads();
    if (st < 127) {
#pragma unroll
      for (int j = 0; j < 4; ++j) {
        *(v8h*)&Bsh[tid][(j << 3)] = cr[j];
        *(v8h*)&Bsh[tid][32 + (j << 3)] = cr[4 + j];
      }
    }
    __syncthreads();
  }

#pragma unroll
  for (int sl = 0; sl < 32; ++sl) {
    float v = mn[sl];
    const u32 byte = (idp[sl >> 2] >> ((sl & 3) << 3)) & 255u;
    u32 code = ((byte >> 1) << 9) + ((u32)w << 6) + ((byte & 1) << 5) + (u32)col;
#pragma unroll
    for (int off = 1; off < 32; off <<= 1) {
      float v2 = __shfl_xor(v, off, 64);
      u32 c2 = (u32)__shfl_xor((int)code, off, 64);
      if (v2 < v || (v2 == v && c2 < code)) { v = v2; code = c2; }
    }
    if (col == 0) {
      const int row = ((sl >> 4) << 5) + (sl & 3) + (((sl >> 2) & 3) << 3) + (hi << 2);
      wredS[w][row] = v; wredC[w][row] = code;
    }
  }
  __syncthreads();
  if (tid < 64) {
    float bv = wredS[0][tid]; u32 bc = wredC[0][tid];
#pragma unroll
    for (int j = 1; j < 8; ++j) {
      float vv = wredS[j][tid]; u32 cc = wredC[j][tid];
      if (vv < bv || (vv == bv && cc < bc)) { bv = vv; bc = cc; }
    }
    finS[tid] = bc;
    out[(size_t)8388608 + ((size_t)b << 10) + (h0 << 5) + tid] = (float)bc;
  }
  __syncthreads();
  {
    const int pt = tid & 63, cg = tid >> 6;
    const u32 code = finS[pt];
    const float4* cbr = cb4 + ((size_t)code << 6);
    const size_t obase = ((size_t)b << 18) + (h0 << 5) + pt;
#pragma unroll
    for (int cc = 0; cc < 8; ++cc) {
      const int c4 = (cc << 3) + cg;
      float4 vv = cbr[c4];
      out[obase + (size_t)((c4 << 2) + 0) * 1024] = vv.x;
      out[obase + (size_t)((c4 << 2) + 1) * 1024] = vv.y;
      out[obase + (size_t)((c4 << 2) + 2) * 1024] = vv.z;
      out[obase + (size_t)((c4 << 2) + 3) * 1024] = vv.w;
    }
  }
}

extern "C" void kernel_launch(void* const* d_in, const int* in_sizes, int n_in,
                              void* d_out, int out_size, void* d_ws, size_t ws_size,
                              hipStream_t stream) {
  const float* x = (const float*)d_in[0];
  const float* cb = (const float*)d_in[1];
  float* out = (float*)d_out;
  float* cnorm = (float*)d_ws;  // 8192 floats at ws[0:32KB)

  cnorm_k<<<2048, 256, 0, stream>>>((const float4*)cb, cnorm);
  if (ws_size >= (size_t)32768 + (size_t)8388608) {
    _Float16* W = (_Float16*)((char*)d_ws + 32768);  // 8 MB split-permuted planes
    split_cb<<<1024, 256, 0, stream>>>((const float4*)cb, W);
    vq_fast<<<512, 512, 0, stream>>>(x, (const float4*)cb, cnorm, W, out);
  } else {
    vq_fb<<<512, 512, 0, stream>>>(x, (const float4*)cb, cnorm, out);
  }
}